// Round 32
// baseline (64.931 us; speedup 1.0000x reference)
//
#include <hip/hip_runtime.h>

// MultiScaleRoIAlign: B=2, N=1000, C=256, crop 7x7, levels 0..4 sizes {256,128,64,32,16}
// Output (B,N,7,7,C) fp32.
//
// R1-R31: golden = XLA:CPU codegen of the reference. R31 (reciprocal-scale +
// fma) was the FIRST chain to zero box A (correct!) but its fma combine also
// zeroed C (golden keeps). This round keeps the reciprocal scale and reverts
// to the faithful separate mul+add combine:
//   s  = fl( fl(dim*Sm1) * fl32(1/6) )     [arcp reciprocal transform]
//   p  = fl(i*s);  in = fl(t + p)          [uncontracted combine]
// A: reciprocal shift pushes combine > Sm1 -> zeroed (matches golden).
// C,V: faithful add's final rounding collapses sub-halfulp excess back to
// exactly Sm1 -> kept (matches golden).

#define N_PER_B   1000
#define N_POS     98000         // B*N*49
#define CCH       256

__global__ __launch_bounds__(256) void roialign_kernel(
    const float* __restrict__ bboxes,
    const float* __restrict__ f0, const float* __restrict__ f1,
    const float* __restrict__ f2, const float* __restrict__ f3,
    const float* __restrict__ f4,
    float* __restrict__ out)
{
    const int wave = threadIdx.x >> 6;
    const int lane = threadIdx.x & 63;
    const int gid  = blockIdx.x * 4 + wave;          // position id, < N_POS (exact)
    const int m    = gid / 49;                        // box id = b*N + n
    const int pos  = gid - m * 49;
    const int iy   = pos / 7;
    const int ix   = pos - iy * 7;
    const int b    = m / N_PER_B;

    // box: [x1,y1,x2,y2] pixels; clip to [0,1024], normalize (exact pow2 scale)
    const float inv = 1.0f / 1024.0f;
    const float x1 = fminf(fmaxf(bboxes[m*4+0], 0.f), 1024.f) * inv;
    const float y1 = fminf(fmaxf(bboxes[m*4+1], 0.f), 1024.f) * inv;
    const float x2 = fminf(fmaxf(bboxes[m*4+2], 0.f), 1024.f) * inv;
    const float y2 = fminf(fmaxf(bboxes[m*4+3], 0.f), 1024.f) * inv;

    const float h = y2 - y1;
    const float w = x2 - x1;

    // level: f32 sqrt/div, correctly-rounded f32 log2 (via f64), half-even
    const float s32 = __fsqrt_rn(h * w);
    const float q32 = __fdiv_rn(s32, 0.0546875f);
    const float t32 = (float)log2((double)q32);
    int level = (int)rintf(t32);
    level = level < 0 ? 0 : (level > 4 ? 4 : level);

    const float* f; int S;
    switch (level) {
        case 0:  f = f0; S = 256; break;
        case 1:  f = f1; S = 128; break;
        case 2:  f = f2; S =  64; break;
        case 3:  f = f3; S =  32; break;
        default: f = f4; S =  16; break;
    }
    const float Sm1 = (float)(S - 1);

    // reciprocal-scale + faithful combine (every op separately f32-rounded):
    const float C6 = 0.16666667f;   // correctly-rounded fl32(1/6)
    float ry = h * Sm1;
    float rx = w * Sm1;
    asm volatile("" : "+v"(ry), "+v"(rx));   // pin fl(dim*Sm1)
    float sy = ry * C6;
    float sx = rx * C6;
    float ty = y1 * Sm1;
    float tx = x1 * Sm1;
    asm volatile("" : "+v"(sy), "+v"(sx), "+v"(ty), "+v"(tx));
    float py = (float)iy * sy;
    float px = (float)ix * sx;
    asm volatile("" : "+v"(py), "+v"(px));   // pin fl(i*s); blocks fma
    const float in_y = ty + py;
    const float in_x = tx + px;

    float4* out4 = (float4*)(out + (size_t)gid * CCH);

    const bool valid = (in_y >= 0.f) && (in_y <= Sm1) && (in_x >= 0.f) && (in_x <= Sm1);
    if (!valid) {
        out4[lane] = make_float4(0.f, 0.f, 0.f, 0.f);
        return;
    }

    const float y0f = floorf(in_y);
    const float x0f = floorf(in_x);
    const float wy  = in_y - y0f;
    const float wx  = in_x - x0f;
    const float omwy = 1.0f - wy;
    const float omwx = 1.0f - wx;

    int y0 = (int)y0f; y0 = y0 < 0 ? 0 : (y0 > S-1 ? S-1 : y0);
    int x0 = (int)x0f; x0 = x0 < 0 ? 0 : (x0 > S-1 ? S-1 : x0);
    const int y1i = y0 + 1 > S-1 ? S-1 : y0 + 1;
    const int x1i = x0 + 1 > S-1 ? S-1 : x0 + 1;

    const float w00 = omwy * omwx;
    const float w01 = omwy * wx;
    const float w10 = wy * omwx;
    const float w11 = wy * wx;

    const size_t bS = (size_t)b * S;
    const float4* p00 = (const float4*)(f + ((bS + y0 ) * S + x0 ) * CCH);
    const float4* p01 = (const float4*)(f + ((bS + y0 ) * S + x1i) * CCH);
    const float4* p10 = (const float4*)(f + ((bS + y1i) * S + x0 ) * CCH);
    const float4* p11 = (const float4*)(f + ((bS + y1i) * S + x1i) * CCH);

    const float4 v00 = p00[lane];
    const float4 v01 = p01[lane];
    const float4 v10 = p10[lane];
    const float4 v11 = p11[lane];

    float4 r;
    r.x = v00.x*w00 + v01.x*w01 + v10.x*w10 + v11.x*w11;
    r.y = v00.y*w00 + v01.y*w01 + v10.y*w10 + v11.y*w11;
    r.z = v00.z*w00 + v01.z*w01 + v10.z*w10 + v11.z*w11;
    r.w = v00.w*w00 + v01.w*w01 + v10.w*w10 + v11.w*w11;

    out4[lane] = r;
}

extern "C" void kernel_launch(void* const* d_in, const int* in_sizes, int n_in,
                              void* d_out, int out_size, void* d_ws, size_t ws_size,
                              hipStream_t stream) {
    const float* bboxes = (const float*)d_in[0];
    const float* f0 = (const float*)d_in[1];
    const float* f1 = (const float*)d_in[2];
    const float* f2 = (const float*)d_in[3];
    const float* f3 = (const float*)d_in[4];
    const float* f4 = (const float*)d_in[5];
    float* out = (float*)d_out;

    // 98000 positions, 4 waves/block -> 24500 blocks of 256 threads
    roialign_kernel<<<N_POS / 4, 256, 0, stream>>>(bboxes, f0, f1, f2, f3, f4, out);
}

// Round 34
// 61.240 us; speedup vs baseline: 1.0603x; 1.0603x over previous
//
#include <hip/hip_runtime.h>

// MultiScaleRoIAlign: B=2, N=1000, C=256, crop 7x7, levels 0..4 sizes {256,128,64,32,16}
// Output (B,N,7,7,C) fp32.
//
// VERIFIED-CORRECT numerics (R32, absmax 0.0156 < 0.093): golden = XLA:CPU
// fast-math chain:
//   s  = fl( fl(dim*Sm1) * fl32(1/6) )     [division -> reciprocal multiply]
//   p  = fl(i*s);  in = fl(t + p)          [uncontracted faithful combine]
//   t  = fl(start*Sm1); valid inclusive [0, Sm1]; level = CR-f32 log2 + rintf.
// DO NOT touch the arithmetic: 31 failed rounds mapped this chain exactly
// (asm barriers are load-bearing — they block hipcc's fma contraction).
//
// R34 = R33 with the compile fix: nontemporal stores need clang native
// vector types (ext_vector_type), not HIP_vector_type float4.

#define N_PER_B   1000
#define N_POS     98000         // B*N*49
#define CCH       256
#define WPB       8             // waves per block

typedef float f32x4 __attribute__((ext_vector_type(4)));

__global__ __launch_bounds__(512) void roialign_kernel(
    const float* __restrict__ bboxes,
    const float* __restrict__ f0, const float* __restrict__ f1,
    const float* __restrict__ f2, const float* __restrict__ f3,
    const float* __restrict__ f4,
    float* __restrict__ out)
{
    const int wave = threadIdx.x >> 6;
    const int lane = threadIdx.x & 63;
    const int gid  = blockIdx.x * WPB + wave;        // position id
    if (gid >= N_POS) return;
    const int m    = gid / 49;                        // box id = b*N + n
    const int pos  = gid - m * 49;
    const int iy   = pos / 7;
    const int ix   = pos - iy * 7;
    const int b    = m / N_PER_B;

    // box: [x1,y1,x2,y2] pixels; clip to [0,1024], normalize (exact pow2 scale)
    const float inv = 1.0f / 1024.0f;
    const float x1 = fminf(fmaxf(bboxes[m*4+0], 0.f), 1024.f) * inv;
    const float y1 = fminf(fmaxf(bboxes[m*4+1], 0.f), 1024.f) * inv;
    const float x2 = fminf(fmaxf(bboxes[m*4+2], 0.f), 1024.f) * inv;
    const float y2 = fminf(fmaxf(bboxes[m*4+3], 0.f), 1024.f) * inv;

    const float h = y2 - y1;
    const float w = x2 - x1;

    // level: f32 sqrt/div, correctly-rounded f32 log2 (via f64), half-even
    const float s32 = __fsqrt_rn(h * w);
    const float q32 = __fdiv_rn(s32, 0.0546875f);
    const float t32 = (float)log2((double)q32);
    int level = (int)rintf(t32);
    level = level < 0 ? 0 : (level > 4 ? 4 : level);

    const float* f; int S;
    switch (level) {
        case 0:  f = f0; S = 256; break;
        case 1:  f = f1; S = 128; break;
        case 2:  f = f2; S =  64; break;
        case 3:  f = f3; S =  32; break;
        default: f = f4; S =  16; break;
    }
    const float Sm1 = (float)(S - 1);

    // reciprocal-scale + faithful combine (every op separately f32-rounded):
    const float C6 = 0.16666667f;   // correctly-rounded fl32(1/6)
    float ry = h * Sm1;
    float rx = w * Sm1;
    asm volatile("" : "+v"(ry), "+v"(rx));   // pin fl(dim*Sm1)
    float sy = ry * C6;
    float sx = rx * C6;
    float ty = y1 * Sm1;
    float tx = x1 * Sm1;
    asm volatile("" : "+v"(sy), "+v"(sx), "+v"(ty), "+v"(tx));
    float py = (float)iy * sy;
    float px = (float)ix * sx;
    asm volatile("" : "+v"(py), "+v"(px));   // pin fl(i*s); blocks fma
    const float in_y = ty + py;
    const float in_x = tx + px;

    f32x4* out4 = (f32x4*)(out + (size_t)gid * CCH);

    const bool valid = (in_y >= 0.f) && (in_y <= Sm1) && (in_x >= 0.f) && (in_x <= Sm1);
    if (!valid) {
        f32x4 z = {0.f, 0.f, 0.f, 0.f};
        __builtin_nontemporal_store(z, &out4[lane]);
        return;
    }

    const float y0f = floorf(in_y);
    const float x0f = floorf(in_x);
    const float wy  = in_y - y0f;
    const float wx  = in_x - x0f;
    const float omwy = 1.0f - wy;
    const float omwx = 1.0f - wx;

    int y0 = (int)y0f; y0 = y0 < 0 ? 0 : (y0 > S-1 ? S-1 : y0);
    int x0 = (int)x0f; x0 = x0 < 0 ? 0 : (x0 > S-1 ? S-1 : x0);
    const int y1i = y0 + 1 > S-1 ? S-1 : y0 + 1;
    const int x1i = x0 + 1 > S-1 ? S-1 : x0 + 1;

    const float w00 = omwy * omwx;
    const float w01 = omwy * wx;
    const float w10 = wy * omwx;
    const float w11 = wy * wx;

    const size_t bS = (size_t)b * S;
    const f32x4* p00 = (const f32x4*)(f + ((bS + y0 ) * S + x0 ) * CCH);
    const f32x4* p01 = (const f32x4*)(f + ((bS + y0 ) * S + x1i) * CCH);
    const f32x4* p10 = (const f32x4*)(f + ((bS + y1i) * S + x0 ) * CCH);
    const f32x4* p11 = (const f32x4*)(f + ((bS + y1i) * S + x1i) * CCH);

    const f32x4 v00 = p00[lane];
    const f32x4 v01 = p01[lane];
    const f32x4 v10 = p10[lane];
    const f32x4 v11 = p11[lane];

    f32x4 r = v00*w00 + v01*w01 + v10*w10 + v11*w11;

    __builtin_nontemporal_store(r, &out4[lane]);
}

extern "C" void kernel_launch(void* const* d_in, const int* in_sizes, int n_in,
                              void* d_out, int out_size, void* d_ws, size_t ws_size,
                              hipStream_t stream) {
    const float* bboxes = (const float*)d_in[0];
    const float* f0 = (const float*)d_in[1];
    const float* f1 = (const float*)d_in[2];
    const float* f2 = (const float*)d_in[3];
    const float* f3 = (const float*)d_in[4];
    const float* f4 = (const float*)d_in[5];
    float* out = (float*)d_out;

    // 98000 positions, 8 waves/block -> 12250 blocks of 512 threads
    roialign_kernel<<<(N_POS + WPB - 1) / WPB, 512, 0, stream>>>(bboxes, f0, f1, f2, f3, f4, out);
}

// Round 36
// 53.617 us; speedup vs baseline: 1.2110x; 1.1422x over previous
//
#include <hip/hip_runtime.h>

// MultiScaleRoIAlign: B=2, N=1000, C=256, crop 7x7, levels 0..4 sizes {256,128,64,32,16}
// Output (B,N,7,7,C) fp32.
//
// VERIFIED-CORRECT numerics (R32/R34, absmax 0.0156 < 0.093): golden = XLA:CPU
// fast-math chain:
//   s  = fl( fl(dim*Sm1) * fl32(1/6) )     [division -> reciprocal multiply]
//   p  = fl(i*s);  in = fl(t + p)          [uncontracted faithful combine]
//   t  = fl(start*Sm1); valid inclusive [0, Sm1]; level = CR-f32 log2 + rintf.
// DO NOT touch the arithmetic: asm barriers are load-bearing (block fma).
//
// R36 = R35 with shadowing fix (swz_r vs blend r). XCD-aware bijective
// blockIdx swizzle: contiguous block runs per XCD -> a box's ~6-7 blocks
// share one L2 and their ~80%-shared corner pixels stay L2-local.

#define N_PER_B   1000
#define N_POS     98000         // B*N*49
#define CCH       256
#define WPB       8             // waves per block
#define NWG       12250         // ceil(N_POS / WPB)
#define NXCD      8

typedef float f32x4 __attribute__((ext_vector_type(4)));

__global__ __launch_bounds__(512) void roialign_kernel(
    const float* __restrict__ bboxes,
    const float* __restrict__ f0, const float* __restrict__ f1,
    const float* __restrict__ f2, const float* __restrict__ f3,
    const float* __restrict__ f4,
    float* __restrict__ out)
{
    // Bijective XCD swizzle (m204): orig%8 = this block's XCD; give each XCD
    // a CONTIGUOUS chunk of the logical block range.
    const int orig  = blockIdx.x;
    const int xcd   = orig % NXCD;
    const int swz_q = NWG / NXCD;          // 1531
    const int swz_r = NWG % NXCD;          // 2
    const int base  = (xcd < swz_r) ? xcd * (swz_q + 1)
                                    : swz_r * (swz_q + 1) + (xcd - swz_r) * swz_q;
    const int wgid  = base + orig / NXCD;

    const int wave = threadIdx.x >> 6;
    const int lane = threadIdx.x & 63;
    const int gid  = wgid * WPB + wave;        // position id
    if (gid >= N_POS) return;
    const int m    = gid / 49;                  // box id = b*N + n
    const int pos  = gid - m * 49;
    const int iy   = pos / 7;
    const int ix   = pos - iy * 7;
    const int b    = m / N_PER_B;

    // box: [x1,y1,x2,y2] pixels; clip to [0,1024], normalize (exact pow2 scale)
    const float inv = 1.0f / 1024.0f;
    const float x1 = fminf(fmaxf(bboxes[m*4+0], 0.f), 1024.f) * inv;
    const float y1 = fminf(fmaxf(bboxes[m*4+1], 0.f), 1024.f) * inv;
    const float x2 = fminf(fmaxf(bboxes[m*4+2], 0.f), 1024.f) * inv;
    const float y2 = fminf(fmaxf(bboxes[m*4+3], 0.f), 1024.f) * inv;

    const float h = y2 - y1;
    const float w = x2 - x1;

    // level: f32 sqrt/div, correctly-rounded f32 log2 (via f64), half-even
    const float s32 = __fsqrt_rn(h * w);
    const float q32 = __fdiv_rn(s32, 0.0546875f);
    const float t32 = (float)log2((double)q32);
    int level = (int)rintf(t32);
    level = level < 0 ? 0 : (level > 4 ? 4 : level);

    const float* f; int S;
    switch (level) {
        case 0:  f = f0; S = 256; break;
        case 1:  f = f1; S = 128; break;
        case 2:  f = f2; S =  64; break;
        case 3:  f = f3; S =  32; break;
        default: f = f4; S =  16; break;
    }
    const float Sm1 = (float)(S - 1);

    // reciprocal-scale + faithful combine (every op separately f32-rounded):
    const float C6 = 0.16666667f;   // correctly-rounded fl32(1/6)
    float ry = h * Sm1;
    float rx = w * Sm1;
    asm volatile("" : "+v"(ry), "+v"(rx));   // pin fl(dim*Sm1)
    float sy = ry * C6;
    float sx = rx * C6;
    float ty = y1 * Sm1;
    float tx = x1 * Sm1;
    asm volatile("" : "+v"(sy), "+v"(sx), "+v"(ty), "+v"(tx));
    float py = (float)iy * sy;
    float px = (float)ix * sx;
    asm volatile("" : "+v"(py), "+v"(px));   // pin fl(i*s); blocks fma
    const float in_y = ty + py;
    const float in_x = tx + px;

    f32x4* out4 = (f32x4*)(out + (size_t)gid * CCH);

    const bool valid = (in_y >= 0.f) && (in_y <= Sm1) && (in_x >= 0.f) && (in_x <= Sm1);
    if (!valid) {
        f32x4 z = {0.f, 0.f, 0.f, 0.f};
        __builtin_nontemporal_store(z, &out4[lane]);
        return;
    }

    const float y0f = floorf(in_y);
    const float x0f = floorf(in_x);
    const float wy  = in_y - y0f;
    const float wx  = in_x - x0f;
    const float omwy = 1.0f - wy;
    const float omwx = 1.0f - wx;

    int y0 = (int)y0f; y0 = y0 < 0 ? 0 : (y0 > S-1 ? S-1 : y0);
    int x0 = (int)x0f; x0 = x0 < 0 ? 0 : (x0 > S-1 ? S-1 : x0);
    const int y1i = y0 + 1 > S-1 ? S-1 : y0 + 1;
    const int x1i = x0 + 1 > S-1 ? S-1 : x0 + 1;

    const float w00 = omwy * omwx;
    const float w01 = omwy * wx;
    const float w10 = wy * omwx;
    const float w11 = wy * wx;

    const size_t bS = (size_t)b * S;
    const f32x4* p00 = (const f32x4*)(f + ((bS + y0 ) * S + x0 ) * CCH);
    const f32x4* p01 = (const f32x4*)(f + ((bS + y0 ) * S + x1i) * CCH);
    const f32x4* p10 = (const f32x4*)(f + ((bS + y1i) * S + x0 ) * CCH);
    const f32x4* p11 = (const f32x4*)(f + ((bS + y1i) * S + x1i) * CCH);

    const f32x4 v00 = p00[lane];
    const f32x4 v01 = p01[lane];
    const f32x4 v10 = p10[lane];
    const f32x4 v11 = p11[lane];

    f32x4 res = v00*w00 + v01*w01 + v10*w10 + v11*w11;

    __builtin_nontemporal_store(res, &out4[lane]);
}

extern "C" void kernel_launch(void* const* d_in, const int* in_sizes, int n_in,
                              void* d_out, int out_size, void* d_ws, size_t ws_size,
                              hipStream_t stream) {
    const float* bboxes = (const float*)d_in[0];
    const float* f0 = (const float*)d_in[1];
    const float* f1 = (const float*)d_in[2];
    const float* f2 = (const float*)d_in[3];
    const float* f3 = (const float*)d_in[4];
    const float* f4 = (const float*)d_in[5];
    float* out = (float*)d_out;

    // 98000 positions, 8 waves/block -> 12250 blocks of 512 threads
    roialign_kernel<<<NWG, 512, 0, stream>>>(bboxes, f0, f1, f2, f3, f4, out);
}